// Round 21
// baseline (394.234 us; speedup 1.0000x reference)
//
#include <hip/hip_runtime.h>
#include <hip/hip_bf16.h>
#include <math.h>

#define NN 16384
#define BB 64
#define NPG 256
#define KNN 100
#define FIN 5
#define HH 128
#define H2 768
#define SLOPE 0.01f

// Inputs are fp32 (verified R3). Dtype detect inline: bn_gamma all-ones -> first 32 bits
// 0x3F800000 (fp32) vs 0x3F803F80 (bf16).
__device__ __forceinline__ int detect_bf(const void* gamma) {
    return ((const unsigned*)gamma)[0] == 0x3F803F80u;
}
__device__ __forceinline__ float loadin(const void* p, size_t i, int bf) {
    return bf ? __bfloat162float(((const __hip_bfloat16*)p)[i]) : ((const float*)p)[i];
}
template <typename T>
__device__ __forceinline__ float ldT(const T* p, size_t i) { return (float)p[i]; }
template <>
__device__ __forceinline__ float ldT<__hip_bfloat16>(const __hip_bfloat16* p, size_t i) {
    return __bfloat162float(p[i]);
}
__device__ __forceinline__ float4 ldT4(const float* p) { return *(const float4*)p; }
__device__ __forceinline__ float4 ldT4(const __hip_bfloat16* p) {
    ushort4 u = *(const ushort4*)p;
    return make_float4(__uint_as_float((unsigned)u.x << 16),
                       __uint_as_float((unsigned)u.y << 16),
                       __uint_as_float((unsigned)u.z << 16),
                       __uint_as_float((unsigned)u.w << 16));
}
__device__ __forceinline__ void stage_chunk(float* dst, const float* src, int n, int t) {
    const float4* s = (const float4*)src;
    float4* d = (float4*)dst;
    int n4 = n >> 2;
    for (int i = t; i < n4; i += 256) d[i] = s[i];
}
__device__ __forceinline__ void stage_chunk(float* dst, const __hip_bfloat16* src, int n, int t) {
    const ushort4* s = (const ushort4*)src;
    int n4 = n >> 2;
    for (int i = t; i < n4; i += 256) {
        ushort4 u = s[i];
        dst[i * 4 + 0] = __uint_as_float((unsigned)u.x << 16);
        dst[i * 4 + 1] = __uint_as_float((unsigned)u.y << 16);
        dst[i * 4 + 2] = __uint_as_float((unsigned)u.z << 16);
        dst[i * 4 + 3] = __uint_as_float((unsigned)u.w << 16);
    }
}

// Order-preserving fp32 <-> u32 map for atomicMax-based max pooling.
__device__ __forceinline__ unsigned enc_f(float f) {
    unsigned u = __float_as_uint(f);
    return (u & 0x80000000u) ? ~u : (u | 0x80000000u);
}
__device__ __forceinline__ float dec_f(unsigned u) {
    return __uint_as_float((u & 0x80000000u) ? (u & 0x7FFFFFFFu) : ~u);
}
// fp32 -> bf16 bits, round-to-nearest-even (finite values only)
__device__ __forceinline__ unsigned f2bf(float f) {
    unsigned u = __float_as_uint(f);
    unsigned r = 0x7fffu + ((u >> 16) & 1u);
    return (u + r) >> 16;
}

// ---------------- KNN v6 + init duties ----------------
// Transposed xg (conflict-free b128 distance reads), wave-per-row bitonic sort,
// 4 keys/lane. Side duties: g pool init (blocks 0..191), outf/done zero (block 0),
// MLP K-split accumulator zero (first 4*BB*H2 threads).
__global__ __launch_bounds__(256) void knn_kernel(const void* __restrict__ x_in,
                                                  const void* gamma,
                                                  unsigned char* __restrict__ nbr,
                                                  float* __restrict__ g,
                                                  float* __restrict__ macc,
                                                  float* __restrict__ outf,
                                                  unsigned* __restrict__ done) {
    int blk = blockIdx.x;
    int bf = detect_bf(gamma);
    int b = blk >> 6;
    int wave = threadIdx.x >> 6;
    int lane = threadIdx.x & 63;
    int il = ((blk & 63) << 2) + wave;
    {
        int gi = blk * 256 + threadIdx.x;
        if (blk < 192 && gi < BB * H2) {
            int cm = gi & 255;
            g[gi] = (cm < 128) ? 0.0f : __uint_as_float(0x007FFFFFu);
        }
        if (gi < 4 * BB * H2) macc[gi] = 0.0f;
        if (blk == 0 && threadIdx.x < BB) {
            outf[threadIdx.x] = 0.0f;
            done[threadIdx.x] = 0u;
        }
    }
    __shared__ float xg[FIN * NPG];   // transposed: xg[c*256 + node]
    for (int idx = threadIdx.x; idx < NPG * FIN; idx += 256) {
        int node = idx / FIN, c = idx - node * FIN;
        xg[c * NPG + node] = loadin(x_in, (size_t)b * NPG * FIN + idx, bf);
    }
    __syncthreads();
    float dq[4] = {0.f, 0.f, 0.f, 0.f};
    #pragma unroll
    for (int c = 0; c < FIN; ++c) {
        float xi = xg[c * NPG + il];                          // broadcast
        float4 xv = *(const float4*)&xg[c * NPG + lane * 4];  // conflict-free b128
        float d0 = xi - xv.x, d1 = xi - xv.y, d2 = xi - xv.z, d3 = xi - xv.w;
        dq[0] += d0 * d0; dq[1] += d1 * d1; dq[2] += d2 * d2; dq[3] += d3 * d3;
    }
    unsigned long long kq[4];
    #pragma unroll
    for (int q = 0; q < 4; ++q) {
        int e = lane * 4 + q;
        float dd = (e == il) ? 1e30f : dq[q];
        kq[q] = ((unsigned long long)__float_as_uint(dd) << 32) | (unsigned)e;
    }
    #pragma unroll
    for (int kk = 2; kk <= NPG; kk <<= 1) {
        #pragma unroll
        for (int j = kk >> 1; j > 0; j >>= 1) {
            unsigned long long nk[4];
            if (j >= 4) {
                int lj = j >> 2;
                #pragma unroll
                for (int q = 0; q < 4; ++q) {
                    unsigned long long pk = __shfl_xor(kq[q], lj, 64);
                    int e = lane * 4 + q;
                    bool keepmin = (((e & j) == 0) == ((e & kk) == 0));
                    unsigned long long mn = kq[q] < pk ? kq[q] : pk;
                    unsigned long long mx = kq[q] < pk ? pk : kq[q];
                    nk[q] = keepmin ? mn : mx;
                }
            } else {
                #pragma unroll
                for (int q = 0; q < 4; ++q) {
                    unsigned long long pk = kq[q ^ j];
                    int e = lane * 4 + q;
                    bool keepmin = (((e & j) == 0) == ((e & kk) == 0));
                    unsigned long long mn = kq[q] < pk ? kq[q] : pk;
                    unsigned long long mx = kq[q] < pk ? pk : kq[q];
                    nk[q] = keepmin ? mn : mx;
                }
            }
            kq[0] = nk[0]; kq[1] = nk[1]; kq[2] = nk[2]; kq[3] = nk[3];
        }
    }
    if (lane < 25) {
        uchar4 o = make_uchar4((unsigned char)kq[0], (unsigned char)kq[1],
                               (unsigned char)kq[2], (unsigned char)kq[3]);
        *(uchar4*)&nbr[(size_t)(b * NPG + il) * KNN + lane * 4] = o;
    }
}

// ---------------- aggregation, C=5, BOTH hops fused (x converted inline) ----------------
__global__ void agg5x2_kernel(const void* __restrict__ x_in, const void* gamma,
                              const unsigned char* __restrict__ nbr,
                              float* __restrict__ t5a, float* __restrict__ t5b, float nrm) {
    int b = blockIdx.x, i = threadIdx.x;
    int bf = detect_bf(gamma);
    __shared__ float xs[NPG * FIN];
    __shared__ float ys[NPG * FIN];
    for (int idx = threadIdx.x; idx < NPG * FIN; idx += 256)
        xs[idx] = loadin(x_in, (size_t)b * NPG * FIN + idx, bf);
    __syncthreads();
    const unsigned char* nb = nbr + (size_t)(b * NPG + i) * KNN;
    float a0=0.f, a1=0.f, a2=0.f, a3=0.f, a4=0.f;
    for (int k = 0; k < KNN; ++k) {
        int base = (int)nb[k] * FIN;
        a0 += xs[base+0]; a1 += xs[base+1]; a2 += xs[base+2];
        a3 += xs[base+3]; a4 += xs[base+4];
    }
    a0 *= nrm; a1 *= nrm; a2 *= nrm; a3 *= nrm; a4 *= nrm;
    size_t o = (size_t)(b * NPG + i) * FIN;
    t5a[o+0] = a0; t5a[o+1] = a1; t5a[o+2] = a2; t5a[o+3] = a3; t5a[o+4] = a4;
    ys[i*FIN+0] = a0; ys[i*FIN+1] = a1; ys[i*FIN+2] = a2;
    ys[i*FIN+3] = a3; ys[i*FIN+4] = a4;
    __syncthreads();
    a0=0.f; a1=0.f; a2=0.f; a3=0.f; a4=0.f;
    for (int k = 0; k < KNN; ++k) {
        int base = (int)nb[k] * FIN;
        a0 += ys[base+0]; a1 += ys[base+1]; a2 += ys[base+2];
        a3 += ys[base+3]; a4 += ys[base+4];
    }
    t5b[o+0] = nrm*a0; t5b[o+1] = nrm*a1; t5b[o+2] = nrm*a2;
    t5b[o+3] = nrm*a3; t5b[o+4] = nrm*a4;
}

// ---------------- aggregation, C=128, bf16 LDS tile ----------------
__global__ __launch_bounds__(256) void agg128_kernel(
        const float* __restrict__ hin, const unsigned char* __restrict__ nbr,
        float* __restrict__ hout, float nrm) {
    int b = blockIdx.x;
    int c0 = blockIdx.y * 32;
    int i0 = blockIdx.z * 128;
    __shared__ unsigned hs[NPG * 20];   // 20 KB
    int t = threadIdx.x;
    for (int i = t; i < NPG * 4; i += 256) {
        int node = i >> 2, qq = i & 3;
        const float* src = &hin[((size_t)(b * NPG + node)) * HH + c0 + qq * 8];
        float4 va = *(const float4*)src;
        float4 vb = *(const float4*)(src + 4);
        unsigned* d = &hs[node * 20 + qq * 4];
        d[0] = f2bf(va.x) | (f2bf(va.y) << 16);
        d[1] = f2bf(va.z) | (f2bf(va.w) << 16);
        d[2] = f2bf(vb.x) | (f2bf(vb.y) << 16);
        d[3] = f2bf(vb.z) | (f2bf(vb.w) << 16);
    }
    __syncthreads();
    int oct = t & 3;
    #pragma unroll
    for (int pass = 0; pass < 2; ++pass) {
        int il = i0 + pass * 64 + (t >> 2);
        const unsigned char* nb = nbr + (size_t)(b * NPG + il) * KNN;
        float a[8] = {0.f,0.f,0.f,0.f,0.f,0.f,0.f,0.f};
        #pragma unroll 5
        for (int k4 = 0; k4 < KNN / 4; ++k4) {
            uchar4 n4 = *(const uchar4*)&nb[k4 * 4];
            const uint4 d0 = *(const uint4*)&hs[(int)n4.x * 20 + oct * 4];
            const uint4 d1 = *(const uint4*)&hs[(int)n4.y * 20 + oct * 4];
            const uint4 d2 = *(const uint4*)&hs[(int)n4.z * 20 + oct * 4];
            const uint4 d3 = *(const uint4*)&hs[(int)n4.w * 20 + oct * 4];
            #pragma unroll
            for (int u = 0; u < 4; ++u) {
                unsigned w0 = (&d0.x)[u], w1 = (&d1.x)[u], w2 = (&d2.x)[u], w3 = (&d3.x)[u];
                a[u*2+0] += __uint_as_float(w0 << 16) + __uint_as_float(w1 << 16)
                          + __uint_as_float(w2 << 16) + __uint_as_float(w3 << 16);
                a[u*2+1] += __uint_as_float(w0 & 0xffff0000u) + __uint_as_float(w1 & 0xffff0000u)
                          + __uint_as_float(w2 & 0xffff0000u) + __uint_as_float(w3 & 0xffff0000u);
            }
        }
        float* po = &hout[((size_t)(b * NPG + il)) * HH + c0 + oct * 8];
        *(float4*)po = make_float4(nrm*a[0], nrm*a[1], nrm*a[2], nrm*a[3]);
        *(float4*)(po + 4) = make_float4(nrm*a[4], nrm*a[5], nrm*a[6], nrm*a[7]);
    }
}

// ---------------- pool epilogue (16-lane-group layout, used by tagmm5) ----------------
__device__ __forceinline__ void pool_epilogue(float* g, int b, int gc0, int cg, int rp,
                                              float* sv, float* mv) {
    #pragma unroll
    for (int mask = 1; mask < 16; mask <<= 1) {
        #pragma unroll
        for (int i = 0; i < 8; ++i) {
            sv[i] += __shfl_xor(sv[i], mask);
            mv[i] = fmaxf(mv[i], __shfl_xor(mv[i], mask));
        }
    }
    if (rp == 0) {
        #pragma unroll
        for (int i = 0; i < 8; ++i) {
            atomicAdd(&g[(size_t)b * H2 + gc0 + cg * 8 + i], sv[i]);
            atomicMax((unsigned*)&g[(size_t)b * H2 + gc0 + HH + cg * 8 + i], enc_f(mv[i]));
        }
    }
}

// ---------------- tagmm5 (+fused pool), X0 converted inline from raw x ----------------
template <typename T>
__device__ __forceinline__ void tagmm5_body(
        const T* __restrict__ X0raw, const float* __restrict__ X1,
        const float* __restrict__ X2,
        const T* __restrict__ W, const T* __restrict__ bias,
        float* __restrict__ O, float* g, float* Ws, float* Xs) {
    int t = threadIdx.x;
    int r0 = blockIdx.x * 16;
    int r = t & 15, cg = t >> 4;
    float acc[8] = {0.f,0.f,0.f,0.f,0.f,0.f,0.f,0.f};
    for (int h = 0; h < 3; ++h) {
        stage_chunk(Ws, W + (size_t)h * FIN * HH, FIN * HH, t);
        for (int idx = t; idx < 16 * FIN; idx += 256) {
            int rr = idx / FIN, k = idx - rr * FIN;
            size_t src = (size_t)(r0 + rr) * FIN + k;
            Xs[rr * 9 + k] = (h == 0) ? ldT(X0raw, src)
                           : (h == 1) ? X1[src] : X2[src];
        }
        __syncthreads();
        #pragma unroll
        for (int k = 0; k < FIN; ++k) {
            float xv = Xs[r * 9 + k];
            const float4 wa = *(const float4*)&Ws[k * HH + cg * 8];
            const float4 wb = *(const float4*)&Ws[k * HH + cg * 8 + 4];
            acc[0] += xv * wa.x; acc[1] += xv * wa.y;
            acc[2] += xv * wa.z; acc[3] += xv * wa.w;
            acc[4] += xv * wb.x; acc[5] += xv * wb.y;
            acc[6] += xv * wb.z; acc[7] += xv * wb.w;
        }
        __syncthreads();
    }
    size_t orow = (size_t)(r0 + r) * HH + cg * 8;
    float sv[8], mv[8];
    #pragma unroll
    for (int m = 0; m < 8; ++m) {
        float v = acc[m] + ldT(bias, cg * 8 + m);
        v = v > 0.f ? v : SLOPE * v;
        O[orow + m] = v;
        sv[m] = v * (1.0f / NPG);
        mv[m] = v;
    }
    pool_epilogue(g, r0 >> 8, 0, cg, r, sv, mv);
}

__global__ __launch_bounds__(256) void tagmm5_kernel(
        const void* X0raw, const float* X1, const float* X2,
        const void* W, const void* bias, float* O, float* g, const void* gamma) {
    __shared__ float Ws[FIN * HH];
    __shared__ float Xs[16 * 9];
    if (detect_bf(gamma))
        tagmm5_body<__hip_bfloat16>((const __hip_bfloat16*)X0raw, X1, X2,
                                    (const __hip_bfloat16*)W,
                                    (const __hip_bfloat16*)bias, O, g, Ws, Xs);
    else
        tagmm5_body<float>((const float*)X0raw, X1, X2, (const float*)W,
                           (const float*)bias, O, g, Ws, Xs);
}

// ---------------- tagmm128 v3 (+fused pool): thread = 4 rows x 4 cols ----------------
template <typename T>
__device__ __forceinline__ void tagmm128_body(
        const float* __restrict__ X0, const float* __restrict__ X1,
        const float* __restrict__ X2,
        const T* __restrict__ W, const T* __restrict__ bias,
        float* __restrict__ O, float* g, int gc0,
        float* Ws, float* Xs, float* psum, float* pmax) {
    int t = threadIdx.x;
    int r0 = blockIdx.x * 32;
    int cgl = t & 31;
    int rg  = t >> 5;
    float acc[4][4];
    #pragma unroll
    for (int a = 0; a < 4; ++a)
        #pragma unroll
        for (int c = 0; c < 4; ++c) acc[a][c] = 0.f;
    const float* Xh[3] = {X0, X1, X2};
    for (int h = 0; h < 3; ++h) {
        const float* X = Xh[h];
        for (int k0 = 0; k0 < HH; k0 += 64) {
            stage_chunk(Ws, W + ((size_t)h * HH + k0) * HH, 64 * HH, t);
            for (int i = t; i < 512; i += 256) {
                int row = i & 31, kq = i >> 5;
                float4 v = *(const float4*)&X[(size_t)(r0 + row) * HH + k0 + kq * 4];
                Xs[(kq * 4 + 0) * 36 + row] = v.x;
                Xs[(kq * 4 + 1) * 36 + row] = v.y;
                Xs[(kq * 4 + 2) * 36 + row] = v.z;
                Xs[(kq * 4 + 3) * 36 + row] = v.w;
            }
            __syncthreads();
            #pragma unroll 8
            for (int k = 0; k < 64; ++k) {
                const float4 xv = *(const float4*)&Xs[k * 36 + rg * 4];
                const float4 wv = *(const float4*)&Ws[k * 128 + cgl * 4];
                acc[0][0] += xv.x * wv.x; acc[0][1] += xv.x * wv.y;
                acc[0][2] += xv.x * wv.z; acc[0][3] += xv.x * wv.w;
                acc[1][0] += xv.y * wv.x; acc[1][1] += xv.y * wv.y;
                acc[1][2] += xv.y * wv.z; acc[1][3] += xv.y * wv.w;
                acc[2][0] += xv.z * wv.x; acc[2][1] += xv.z * wv.y;
                acc[2][2] += xv.z * wv.z; acc[2][3] += xv.z * wv.w;
                acc[3][0] += xv.w * wv.x; acc[3][1] += xv.w * wv.y;
                acc[3][2] += xv.w * wv.z; acc[3][3] += xv.w * wv.w;
            }
            __syncthreads();
        }
    }
    float bv[4];
    #pragma unroll
    for (int c = 0; c < 4; ++c) bv[c] = ldT(bias, cgl * 4 + c);
    float sv[4] = {0.f, 0.f, 0.f, 0.f};
    float mv[4] = {-INFINITY, -INFINITY, -INFINITY, -INFINITY};
    #pragma unroll
    for (int rr = 0; rr < 4; ++rr) {
        float4 ov;
        float* po = (float*)&ov;
        #pragma unroll
        for (int c = 0; c < 4; ++c) {
            float v = acc[rr][c] + bv[c];
            v = v > 0.f ? v : SLOPE * v;
            po[c] = v;
            sv[c] += v;
            mv[c] = fmaxf(mv[c], v);
        }
        *(float4*)&O[(size_t)(r0 + rg * 4 + rr) * HH + cgl * 4] = ov;
    }
    #pragma unroll
    for (int c = 0; c < 4; ++c) {
        sv[c] += __shfl_xor(sv[c], 32);
        mv[c] = fmaxf(mv[c], __shfl_xor(mv[c], 32));
    }
    int wave = t >> 6, lane = t & 63;
    if (lane < 32) {
        #pragma unroll
        for (int c = 0; c < 4; ++c) {
            psum[wave * 128 + cgl * 4 + c] = sv[c];
            pmax[wave * 128 + cgl * 4 + c] = mv[c];
        }
    }
    __syncthreads();
    if (t < 128) {
        float s = psum[t] + psum[128 + t] + psum[256 + t] + psum[384 + t];
        float m = fmaxf(fmaxf(pmax[t], pmax[128 + t]), fmaxf(pmax[256 + t], pmax[384 + t]));
        int b = r0 >> 8;
        atomicAdd(&g[(size_t)b * H2 + gc0 + t], s * (1.0f / NPG));
        atomicMax((unsigned*)&g[(size_t)b * H2 + gc0 + HH + t], enc_f(m));
    }
}

__global__ __launch_bounds__(256) void tagmm128_kernel(
        const float* X0, const float* X1, const float* X2,
        const void* W, const void* bias, float* O, float* g, int gc0, const void* gamma) {
    __shared__ float Ws[64 * HH];
    __shared__ float Xs[64 * 36];
    __shared__ float psum[4 * 128];
    __shared__ float pmax[4 * 128];
    if (detect_bf(gamma))
        tagmm128_body<__hip_bfloat16>(X0, X1, X2, (const __hip_bfloat16*)W,
                                      (const __hip_bfloat16*)bias, O, g, gc0,
                                      Ws, Xs, psum, pmax);
    else
        tagmm128_body<float>(X0, X1, X2, (const float*)W, (const float*)bias,
                             O, g, gc0, Ws, Xs, psum, pmax);
}

// ---------------- batchnorm: one-pass sum/sumsq, decode pool accumulators ----------------
__global__ void bn_kernel(float* __restrict__ g, const void* gamma, const void* beta) {
    int c = blockIdx.x * 128 + threadIdx.x;
    int bf = detect_bf(gamma);
    int ismax = (c & 255) >= 128;
    float s = 0.f, s2 = 0.f;
    #pragma unroll 8
    for (int b = 0; b < BB; ++b) {
        float raw = g[(size_t)b * H2 + c];
        float x = ismax ? dec_f(__float_as_uint(raw)) : raw;
        s += x; s2 += x * x;
    }
    float mu = s * (1.0f / BB);
    float var = fmaxf(s2 * (1.0f / BB) - mu * mu, 0.f);
    float rs = 1.0f / sqrtf(var + 1e-5f);
    float ga = loadin(gamma, c, bf), be = loadin(beta, c, bf);
    #pragma unroll 8
    for (int b = 0; b < BB; ++b) {
        float raw = g[(size_t)b * H2 + c];
        float x = ismax ? dec_f(__float_as_uint(raw)) : raw;
        g[(size_t)b * H2 + c] = (x - mu) * rs * ga + be;
    }
}

// ---------------- MLP layers 0-3: K-split x4 ----------------
// grid (48, 4): block (cx, ky) computes cols [cx*16,+16) over K chunk [ky*192,+192)
// (3 stages of 64). Partials atomicAdd into pre-zeroed O (knn zeroes macc); bias added
// by the ky==0 block. Output is PRE-activation; consumers apply leaky on X load (lkin).
// Xs stride 65: read bank (r+k)%32, conflict-free (R19's stride-68 b128 was 8-way).
template <typename T>
__device__ __forceinline__ void mlp_split_body(
        const float* __restrict__ X, const T* __restrict__ W, const T* __restrict__ bias,
        float* __restrict__ O, int lkin, float* Xs, float* Ws) {
    int t = threadIdx.x;
    int col0 = blockIdx.x * 16;
    int kbase = blockIdx.y * 192;
    int r = t & 63, cg = t >> 6;
    float acc[4] = {0.f, 0.f, 0.f, 0.f};
    const float4* Xg = (const float4*)X;
    int kr = t >> 2, c4 = t & 3;
    for (int s = 0; s < 3; ++s) {
        int k0 = kbase + s * 64;
        #pragma unroll
        for (int u = 0; u < 4; ++u) {
            int i = t + u * 256;
            float4 v = Xg[(size_t)(i >> 4) * (H2 / 4) + (k0 >> 2) + (i & 15)];
            if (lkin) {
                v.x = v.x > 0.f ? v.x : SLOPE * v.x;
                v.y = v.y > 0.f ? v.y : SLOPE * v.y;
                v.z = v.z > 0.f ? v.z : SLOPE * v.z;
                v.w = v.w > 0.f ? v.w : SLOPE * v.w;
            }
            float* d = &Xs[(i >> 4) * 65 + (i & 15) * 4];
            d[0] = v.x; d[1] = v.y; d[2] = v.z; d[3] = v.w;
        }
        {
            float4 v = ldT4(W + (size_t)(k0 + kr) * H2 + col0 + c4 * 4);
            float* d = &Ws[kr * 16 + c4 * 4];
            d[0] = v.x; d[1] = v.y; d[2] = v.z; d[3] = v.w;
        }
        __syncthreads();
        #pragma unroll 8
        for (int k = 0; k < 64; ++k) {
            float xv = Xs[r * 65 + k];
            const float4 wv = *(const float4*)&Ws[k * 16 + cg * 4];
            acc[0] += xv * wv.x; acc[1] += xv * wv.y;
            acc[2] += xv * wv.z; acc[3] += xv * wv.w;
        }
        __syncthreads();
    }
    size_t o = (size_t)r * H2 + col0 + cg * 4;
    #pragma unroll
    for (int m = 0; m < 4; ++m) {
        float v = acc[m];
        if (blockIdx.y == 0) v += ldT(bias, col0 + cg * 4 + m);
        atomicAdd(&O[o + m], v);
    }
}

__global__ __launch_bounds__(256) void mlp_split_kernel(
        const float* X, const void* W, size_t woff, const void* bias, size_t boff,
        float* O, int lkin, const void* gamma) {
    __shared__ float Xs[64 * 65];
    __shared__ float Ws[64 * 16];
    if (detect_bf(gamma))
        mlp_split_body<__hip_bfloat16>(X, (const __hip_bfloat16*)W + woff,
                                       (const __hip_bfloat16*)bias + boff, O, lkin, Xs, Ws);
    else
        mlp_split_body<float>(X, (const float*)W + woff,
                              (const float*)bias + boff, O, lkin, Xs, Ws);
}

// ---------------- MLP layer 4 (full-K, dbuf, lkin on X) + fused final dot ---------------
template <typename T>
__device__ __forceinline__ void mlp_layer_body(
        const float* __restrict__ X, const T* __restrict__ W, const T* __restrict__ bias,
        float* Xs0, float* Xs1, float* Ws0, float* Ws1, float* acc_out) {
    int t = threadIdx.x;
    int col0 = blockIdx.x * 16;
    int r = t & 63, cg = t >> 6;
    float acc[4] = {0.f, 0.f, 0.f, 0.f};
    const float4* Xg = (const float4*)X;
    float4 xr[4]; float4 wr;
    int kr = t >> 2, c4 = t & 3;
    #pragma unroll
    for (int u = 0; u < 4; ++u) {
        int i = t + u * 256;
        float4 v = Xg[(size_t)(i >> 4) * (H2 / 4) + (i & 15)];
        v.x = v.x > 0.f ? v.x : SLOPE * v.x;
        v.y = v.y > 0.f ? v.y : SLOPE * v.y;
        v.z = v.z > 0.f ? v.z : SLOPE * v.z;
        v.w = v.w > 0.f ? v.w : SLOPE * v.w;
        xr[u] = v;
    }
    wr = ldT4(W + (size_t)kr * H2 + col0 + c4 * 4);
    {
        #pragma unroll
        for (int u = 0; u < 4; ++u) {
            int i = t + u * 256;
            float* d = &Xs0[(i >> 4) * 65 + (i & 15) * 4];
            d[0] = xr[u].x; d[1] = xr[u].y; d[2] = xr[u].z; d[3] = xr[u].w;
        }
        float* d = &Ws0[kr * 16 + c4 * 4];
        d[0] = wr.x; d[1] = wr.y; d[2] = wr.z; d[3] = wr.w;
    }
    __syncthreads();
    for (int s = 0; s < 12; ++s) {
        if (s + 1 < 12) {
            int k0 = (s + 1) * 64;
            #pragma unroll
            for (int u = 0; u < 4; ++u) {
                int i = t + u * 256;
                float4 v = Xg[(size_t)(i >> 4) * (H2 / 4) + (k0 >> 2) + (i & 15)];
                v.x = v.x > 0.f ? v.x : SLOPE * v.x;
                v.y = v.y > 0.f ? v.y : SLOPE * v.y;
                v.z = v.z > 0.f ? v.z : SLOPE * v.z;
                v.w = v.w > 0.f ? v.w : SLOPE * v.w;
                xr[u] = v;
            }
            wr = ldT4(W + (size_t)(k0 + kr) * H2 + col0 + c4 * 4);
        }
        const float* Xc = (s & 1) ? Xs1 : Xs0;
        const float* Wc = (s & 1) ? Ws1 : Ws0;
        #pragma unroll 8
        for (int k = 0; k < 64; ++k) {
            float xv = Xc[r * 65 + k];
            const float4 wv = *(const float4*)&Wc[k * 16 + cg * 4];
            acc[0] += xv * wv.x; acc[1] += xv * wv.y;
            acc[2] += xv * wv.z; acc[3] += xv * wv.w;
        }
        if (s + 1 < 12) {
            float* Xn = (s & 1) ? Xs0 : Xs1;
            float* Wn = (s & 1) ? Ws0 : Ws1;
            #pragma unroll
            for (int u = 0; u < 4; ++u) {
                int i = t + u * 256;
                float* d = &Xn[(i >> 4) * 65 + (i & 15) * 4];
                d[0] = xr[u].x; d[1] = xr[u].y; d[2] = xr[u].z; d[3] = xr[u].w;
            }
            float* d = &Wn[kr * 16 + c4 * 4];
            d[0] = wr.x; d[1] = wr.y; d[2] = wr.z; d[3] = wr.w;
            __syncthreads();
        }
    }
    #pragma unroll
    for (int m = 0; m < 4; ++m) {
        float v = acc[m] + ldT(bias, col0 + cg * 4 + m);
        acc_out[m] = v > 0.f ? v : SLOPE * v;
    }
}

template <typename T>
__device__ __forceinline__ void mlp_last_body(
        const float* __restrict__ X, const T* __restrict__ W, const T* __restrict__ bias,
        const T* __restrict__ ow, const T* __restrict__ ob,
        float* __restrict__ outf, unsigned* __restrict__ done, void* out, int bf,
        float* Xs0, float* Xs1, float* Ws0, float* Ws1, float* red) {
    int t = threadIdx.x;
    int col0 = blockIdx.x * 16;
    int r = t & 63, cg = t >> 6;
    float vout[4];
    mlp_layer_body<T>(X, W, bias, Xs0, Xs1, Ws0, Ws1, vout);
    float p = 0.f;
    #pragma unroll
    for (int m = 0; m < 4; ++m)
        p += vout[m] * ldT(ow, col0 + cg * 4 + m);
    red[cg * 64 + r] = p;
    __syncthreads();
    if (t < BB) {
        float s = red[t] + red[64 + t] + red[128 + t] + red[192 + t];
        atomicAdd(&outf[t], s);
        __threadfence();
        unsigned ticket = atomicAdd(&done[t], 1u);
        if (ticket == 47u) {
            __threadfence();
            float v = outf[t] + ldT(ob, 0);
            if (bf) ((__hip_bfloat16*)out)[t] = __float2bfloat16(v);
            else    ((float*)out)[t] = v;
        }
    }
}

__global__ __launch_bounds__(256) void mlp_last_kernel(
        const float* X, const void* W, size_t woff, const void* bias, size_t boff,
        const void* ow, const void* ob, float* outf, unsigned* done, void* out,
        const void* gamma) {
    __shared__ float Xs0[64 * 65], Xs1[64 * 65];
    __shared__ float Ws0[64 * 16], Ws1[64 * 16];
    __shared__ float red[4 * 64];
    if (detect_bf(gamma))
        mlp_last_body<__hip_bfloat16>(X, (const __hip_bfloat16*)W + woff,
                                      (const __hip_bfloat16*)bias + boff,
                                      (const __hip_bfloat16*)ow, (const __hip_bfloat16*)ob,
                                      outf, done, out, 1, Xs0, Xs1, Ws0, Ws1, red);
    else
        mlp_last_body<float>(X, (const float*)W + woff, (const float*)bias + boff,
                             (const float*)ow, (const float*)ob,
                             outf, done, out, 0, Xs0, Xs1, Ws0, Ws1, red);
}

extern "C" void kernel_launch(void* const* d_in, const int* in_sizes, int n_in,
                              void* d_out, int out_size, void* d_ws, size_t ws_size,
                              hipStream_t stream) {
    const void* x_in = d_in[0];
    const void* c1w = d_in[2];  const void* c1b = d_in[3];
    const void* c2w = d_in[4];  const void* c2b = d_in[5];
    const void* c3w = d_in[6];  const void* c3b = d_in[7];
    const void* gam = d_in[8];  const void* bet = d_in[9];
    const void* lw  = d_in[10]; const void* lb  = d_in[11];
    const void* ow  = d_in[12]; const void* obb = d_in[13];

    char* w = (char*)d_ws;
    unsigned char* nbr = (unsigned char*)w;  w += (size_t)NN * KNN;
    float* t5a = (float*)w;                  w += (size_t)NN * FIN * 4;
    float* t5b = (float*)w;                  w += (size_t)NN * FIN * 4;
    float* bufA = (float*)w;                 w += (size_t)NN * HH * 4;
    float* bufB = (float*)w;                 w += (size_t)NN * HH * 4;
    float* bufC = (float*)w;                 w += (size_t)NN * HH * 4;
    float* bufD = (float*)w;                 w += (size_t)NN * HH * 4;
    float* g = (float*)w;                    w += (size_t)BB * H2 * 4;
    float* macc = (float*)w;                 w += (size_t)4 * BB * H2 * 4;   // m0..m3
    float* outf = (float*)w;                 w += (size_t)BB * 4;
    unsigned* done = (unsigned*)w;           w += (size_t)BB * 4;

    float dinv = 1.0f / sqrtf((float)KNN);
    float nrm = dinv * dinv;

    knn_kernel<<<NN / 4, 256, 0, stream>>>(x_in, gam, nbr, g, macc, outf, done);

    dim3 conv_grid32(NN / 32);
    dim3 agg_grid(BB, 4, 2);

    // ---- conv1 (Cin=5) ----
    agg5x2_kernel<<<BB, 256, 0, stream>>>(x_in, gam, nbr, t5a, t5b, nrm);
    tagmm5_kernel<<<NN / 16, 256, 0, stream>>>(x_in, t5a, t5b, c1w, c1b, bufA, g, gam);

    // ---- conv2: bufA -> bufD (+pool @256) ----
    agg128_kernel<<<agg_grid, 256, 0, stream>>>(bufA, nbr, bufB, nrm);
    agg128_kernel<<<agg_grid, 256, 0, stream>>>(bufB, nbr, bufC, nrm);
    tagmm128_kernel<<<conv_grid32, 256, 0, stream>>>(bufA, bufB, bufC, c2w, c2b,
                                                     bufD, g, 256, gam);

    // ---- conv3: bufD -> bufC (+pool @512) ----
    agg128_kernel<<<agg_grid, 256, 0, stream>>>(bufD, nbr, bufA, nrm);
    agg128_kernel<<<agg_grid, 256, 0, stream>>>(bufA, nbr, bufB, nrm);
    tagmm128_kernel<<<conv_grid32, 256, 0, stream>>>(bufD, bufA, bufB, c3w, c3b,
                                                     bufC, g, 512, gam);

    // ---- batchnorm ----
    bn_kernel<<<6, 128, 0, stream>>>(g, gam, bet);

    // ---- MLP: layers 0-3 K-split x4 (deferred leaky), layer 4 + final dot fused ----
    dim3 mlp_grid(H2 / 16, 4);
    float* src = g;
    for (int i = 0; i < 4; ++i) {
        float* dst = macc + (size_t)i * BB * H2;
        mlp_split_kernel<<<mlp_grid, 256, 0, stream>>>(src, lw, (size_t)i * H2 * H2,
                                                       lb, (size_t)i * H2, dst,
                                                       i > 0 ? 1 : 0, gam);
        src = dst;
    }
    mlp_last_kernel<<<H2 / 16, 256, 0, stream>>>(src, lw, (size_t)4 * H2 * H2,
                                                 lb, (size_t)4 * H2, ow, obb,
                                                 outf, done, d_out, gam);
}

// Round 22
// 371.734 us; speedup vs baseline: 1.0605x; 1.0605x over previous
//
#include <hip/hip_runtime.h>
#include <hip/hip_bf16.h>
#include <math.h>

#define NN 16384
#define BB 64
#define NPG 256
#define KNN 100
#define FIN 5
#define HH 128
#define H2 768
#define SLOPE 0.01f

// Inputs are fp32 (verified R3). Dtype detect inline: bn_gamma all-ones -> first 32 bits
// 0x3F800000 (fp32) vs 0x3F803F80 (bf16).
__device__ __forceinline__ int detect_bf(const void* gamma) {
    return ((const unsigned*)gamma)[0] == 0x3F803F80u;
}
__device__ __forceinline__ float loadin(const void* p, size_t i, int bf) {
    return bf ? __bfloat162float(((const __hip_bfloat16*)p)[i]) : ((const float*)p)[i];
}
template <typename T>
__device__ __forceinline__ float ldT(const T* p, size_t i) { return (float)p[i]; }
template <>
__device__ __forceinline__ float ldT<__hip_bfloat16>(const __hip_bfloat16* p, size_t i) {
    return __bfloat162float(p[i]);
}
__device__ __forceinline__ float4 ldT4(const float* p) { return *(const float4*)p; }
__device__ __forceinline__ float4 ldT4(const __hip_bfloat16* p) {
    ushort4 u = *(const ushort4*)p;
    return make_float4(__uint_as_float((unsigned)u.x << 16),
                       __uint_as_float((unsigned)u.y << 16),
                       __uint_as_float((unsigned)u.z << 16),
                       __uint_as_float((unsigned)u.w << 16));
}
__device__ __forceinline__ void stage_chunk(float* dst, const float* src, int n, int t) {
    const float4* s = (const float4*)src;
    float4* d = (float4*)dst;
    int n4 = n >> 2;
    for (int i = t; i < n4; i += 256) d[i] = s[i];
}
__device__ __forceinline__ void stage_chunk(float* dst, const __hip_bfloat16* src, int n, int t) {
    const ushort4* s = (const ushort4*)src;
    int n4 = n >> 2;
    for (int i = t; i < n4; i += 256) {
        ushort4 u = s[i];
        dst[i * 4 + 0] = __uint_as_float((unsigned)u.x << 16);
        dst[i * 4 + 1] = __uint_as_float((unsigned)u.y << 16);
        dst[i * 4 + 2] = __uint_as_float((unsigned)u.z << 16);
        dst[i * 4 + 3] = __uint_as_float((unsigned)u.w << 16);
    }
}

// Order-preserving fp32 <-> u32 map for atomicMax-based max pooling.
__device__ __forceinline__ unsigned enc_f(float f) {
    unsigned u = __float_as_uint(f);
    return (u & 0x80000000u) ? ~u : (u | 0x80000000u);
}
__device__ __forceinline__ float dec_f(unsigned u) {
    return __uint_as_float((u & 0x80000000u) ? (u & 0x7FFFFFFFu) : ~u);
}
// fp32 -> bf16 bits, round-to-nearest-even (finite values only)
__device__ __forceinline__ unsigned f2bf(float f) {
    unsigned u = __float_as_uint(f);
    unsigned r = 0x7fffu + ((u >> 16) & 1u);
    return (u + r) >> 16;
}

// ---------------- KNN v6: transposed xg (conflict-free distance reads) ----------------
// xg_t[c][node]: distance reads are per-lane float4 at 16*lane byte offsets (conflict-free
// b128; the old node*5 layout measured 1.57M SQ_LDS_BANK_CONFLICT). Sort: wave-per-row
// bitonic, 4 keys/lane. Side duties: g pool init (blocks 0..191), outf/done zero (block 0).
__global__ __launch_bounds__(256) void knn_kernel(const void* __restrict__ x_in,
                                                  const void* gamma,
                                                  unsigned char* __restrict__ nbr,
                                                  float* __restrict__ g,
                                                  float* __restrict__ outf,
                                                  unsigned* __restrict__ done) {
    int blk = blockIdx.x;
    int bf = detect_bf(gamma);
    int b = blk >> 6;
    int wave = threadIdx.x >> 6;
    int lane = threadIdx.x & 63;
    int il = ((blk & 63) << 2) + wave;
    {
        int gi = blk * 256 + threadIdx.x;
        if (blk < 192 && gi < BB * H2) {
            int cm = gi & 255;
            g[gi] = (cm < 128) ? 0.0f : __uint_as_float(0x007FFFFFu);
        }
        if (blk == 0 && threadIdx.x < BB) {
            outf[threadIdx.x] = 0.0f;
            done[threadIdx.x] = 0u;
        }
    }
    __shared__ float xg[FIN * NPG];   // transposed: xg[c*256 + node]
    for (int idx = threadIdx.x; idx < NPG * FIN; idx += 256) {
        int node = idx / FIN, c = idx - node * FIN;
        xg[c * NPG + node] = loadin(x_in, (size_t)b * NPG * FIN + idx, bf);
    }
    __syncthreads();
    float dq[4] = {0.f, 0.f, 0.f, 0.f};
    #pragma unroll
    for (int c = 0; c < FIN; ++c) {
        float xi = xg[c * NPG + il];                          // broadcast
        float4 xv = *(const float4*)&xg[c * NPG + lane * 4];  // conflict-free b128
        float d0 = xi - xv.x, d1 = xi - xv.y, d2 = xi - xv.z, d3 = xi - xv.w;
        dq[0] += d0 * d0; dq[1] += d1 * d1; dq[2] += d2 * d2; dq[3] += d3 * d3;
    }
    unsigned long long kq[4];
    #pragma unroll
    for (int q = 0; q < 4; ++q) {
        int e = lane * 4 + q;
        float dd = (e == il) ? 1e30f : dq[q];
        kq[q] = ((unsigned long long)__float_as_uint(dd) << 32) | (unsigned)e;
    }
    #pragma unroll
    for (int kk = 2; kk <= NPG; kk <<= 1) {
        #pragma unroll
        for (int j = kk >> 1; j > 0; j >>= 1) {
            unsigned long long nk[4];
            if (j >= 4) {
                int lj = j >> 2;
                #pragma unroll
                for (int q = 0; q < 4; ++q) {
                    unsigned long long pk = __shfl_xor(kq[q], lj, 64);
                    int e = lane * 4 + q;
                    bool keepmin = (((e & j) == 0) == ((e & kk) == 0));
                    unsigned long long mn = kq[q] < pk ? kq[q] : pk;
                    unsigned long long mx = kq[q] < pk ? pk : kq[q];
                    nk[q] = keepmin ? mn : mx;
                }
            } else {
                #pragma unroll
                for (int q = 0; q < 4; ++q) {
                    unsigned long long pk = kq[q ^ j];
                    int e = lane * 4 + q;
                    bool keepmin = (((e & j) == 0) == ((e & kk) == 0));
                    unsigned long long mn = kq[q] < pk ? kq[q] : pk;
                    unsigned long long mx = kq[q] < pk ? pk : kq[q];
                    nk[q] = keepmin ? mn : mx;
                }
            }
            kq[0] = nk[0]; kq[1] = nk[1]; kq[2] = nk[2]; kq[3] = nk[3];
        }
    }
    if (lane < 25) {
        uchar4 o = make_uchar4((unsigned char)kq[0], (unsigned char)kq[1],
                               (unsigned char)kq[2], (unsigned char)kq[3]);
        *(uchar4*)&nbr[(size_t)(b * NPG + il) * KNN + lane * 4] = o;
    }
}

// ---------------- aggregation, C=5, BOTH hops fused (x converted inline) ----------------
__global__ void agg5x2_kernel(const void* __restrict__ x_in, const void* gamma,
                              const unsigned char* __restrict__ nbr,
                              float* __restrict__ t5a, float* __restrict__ t5b, float nrm) {
    int b = blockIdx.x, i = threadIdx.x;
    int bf = detect_bf(gamma);
    __shared__ float xs[NPG * FIN];
    __shared__ float ys[NPG * FIN];
    for (int idx = threadIdx.x; idx < NPG * FIN; idx += 256)
        xs[idx] = loadin(x_in, (size_t)b * NPG * FIN + idx, bf);
    __syncthreads();
    const unsigned char* nb = nbr + (size_t)(b * NPG + i) * KNN;
    float a0=0.f, a1=0.f, a2=0.f, a3=0.f, a4=0.f;
    for (int k = 0; k < KNN; ++k) {
        int base = (int)nb[k] * FIN;
        a0 += xs[base+0]; a1 += xs[base+1]; a2 += xs[base+2];
        a3 += xs[base+3]; a4 += xs[base+4];
    }
    a0 *= nrm; a1 *= nrm; a2 *= nrm; a3 *= nrm; a4 *= nrm;
    size_t o = (size_t)(b * NPG + i) * FIN;
    t5a[o+0] = a0; t5a[o+1] = a1; t5a[o+2] = a2; t5a[o+3] = a3; t5a[o+4] = a4;
    ys[i*FIN+0] = a0; ys[i*FIN+1] = a1; ys[i*FIN+2] = a2;
    ys[i*FIN+3] = a3; ys[i*FIN+4] = a4;
    __syncthreads();
    a0=0.f; a1=0.f; a2=0.f; a3=0.f; a4=0.f;
    for (int k = 0; k < KNN; ++k) {
        int base = (int)nb[k] * FIN;
        a0 += ys[base+0]; a1 += ys[base+1]; a2 += ys[base+2];
        a3 += ys[base+3]; a4 += ys[base+4];
    }
    t5b[o+0] = nrm*a0; t5b[o+1] = nrm*a1; t5b[o+2] = nrm*a2;
    t5b[o+3] = nrm*a3; t5b[o+4] = nrm*a4;
}

// ---------------- aggregation, C=128, bf16 LDS tile ----------------
__global__ __launch_bounds__(256) void agg128_kernel(
        const float* __restrict__ hin, const unsigned char* __restrict__ nbr,
        float* __restrict__ hout, float nrm) {
    int b = blockIdx.x;
    int c0 = blockIdx.y * 32;
    int i0 = blockIdx.z * 128;
    __shared__ unsigned hs[NPG * 20];   // 20 KB
    int t = threadIdx.x;
    for (int i = t; i < NPG * 4; i += 256) {
        int node = i >> 2, qq = i & 3;
        const float* src = &hin[((size_t)(b * NPG + node)) * HH + c0 + qq * 8];
        float4 va = *(const float4*)src;
        float4 vb = *(const float4*)(src + 4);
        unsigned* d = &hs[node * 20 + qq * 4];
        d[0] = f2bf(va.x) | (f2bf(va.y) << 16);
        d[1] = f2bf(va.z) | (f2bf(va.w) << 16);
        d[2] = f2bf(vb.x) | (f2bf(vb.y) << 16);
        d[3] = f2bf(vb.z) | (f2bf(vb.w) << 16);
    }
    __syncthreads();
    int oct = t & 3;
    #pragma unroll
    for (int pass = 0; pass < 2; ++pass) {
        int il = i0 + pass * 64 + (t >> 2);
        const unsigned char* nb = nbr + (size_t)(b * NPG + il) * KNN;
        float a[8] = {0.f,0.f,0.f,0.f,0.f,0.f,0.f,0.f};
        #pragma unroll 5
        for (int k4 = 0; k4 < KNN / 4; ++k4) {
            uchar4 n4 = *(const uchar4*)&nb[k4 * 4];
            const uint4 d0 = *(const uint4*)&hs[(int)n4.x * 20 + oct * 4];
            const uint4 d1 = *(const uint4*)&hs[(int)n4.y * 20 + oct * 4];
            const uint4 d2 = *(const uint4*)&hs[(int)n4.z * 20 + oct * 4];
            const uint4 d3 = *(const uint4*)&hs[(int)n4.w * 20 + oct * 4];
            #pragma unroll
            for (int u = 0; u < 4; ++u) {
                unsigned w0 = (&d0.x)[u], w1 = (&d1.x)[u], w2 = (&d2.x)[u], w3 = (&d3.x)[u];
                a[u*2+0] += __uint_as_float(w0 << 16) + __uint_as_float(w1 << 16)
                          + __uint_as_float(w2 << 16) + __uint_as_float(w3 << 16);
                a[u*2+1] += __uint_as_float(w0 & 0xffff0000u) + __uint_as_float(w1 & 0xffff0000u)
                          + __uint_as_float(w2 & 0xffff0000u) + __uint_as_float(w3 & 0xffff0000u);
            }
        }
        float* po = &hout[((size_t)(b * NPG + il)) * HH + c0 + oct * 8];
        *(float4*)po = make_float4(nrm*a[0], nrm*a[1], nrm*a[2], nrm*a[3]);
        *(float4*)(po + 4) = make_float4(nrm*a[4], nrm*a[5], nrm*a[6], nrm*a[7]);
    }
}

// ---------------- pool epilogue (16-lane-group layout, used by tagmm5) ----------------
__device__ __forceinline__ void pool_epilogue(float* g, int b, int gc0, int cg, int rp,
                                              float* sv, float* mv) {
    #pragma unroll
    for (int mask = 1; mask < 16; mask <<= 1) {
        #pragma unroll
        for (int i = 0; i < 8; ++i) {
            sv[i] += __shfl_xor(sv[i], mask);
            mv[i] = fmaxf(mv[i], __shfl_xor(mv[i], mask));
        }
    }
    if (rp == 0) {
        #pragma unroll
        for (int i = 0; i < 8; ++i) {
            atomicAdd(&g[(size_t)b * H2 + gc0 + cg * 8 + i], sv[i]);
            atomicMax((unsigned*)&g[(size_t)b * H2 + gc0 + HH + cg * 8 + i], enc_f(mv[i]));
        }
    }
}

// ---------------- tagmm5 (+fused pool), X0 converted inline from raw x ----------------
template <typename T>
__device__ __forceinline__ void tagmm5_body(
        const T* __restrict__ X0raw, const float* __restrict__ X1,
        const float* __restrict__ X2,
        const T* __restrict__ W, const T* __restrict__ bias,
        float* __restrict__ O, float* g, float* Ws, float* Xs) {
    int t = threadIdx.x;
    int r0 = blockIdx.x * 16;
    int r = t & 15, cg = t >> 4;
    float acc[8] = {0.f,0.f,0.f,0.f,0.f,0.f,0.f,0.f};
    for (int h = 0; h < 3; ++h) {
        stage_chunk(Ws, W + (size_t)h * FIN * HH, FIN * HH, t);
        for (int idx = t; idx < 16 * FIN; idx += 256) {
            int rr = idx / FIN, k = idx - rr * FIN;
            size_t src = (size_t)(r0 + rr) * FIN + k;
            Xs[rr * 9 + k] = (h == 0) ? ldT(X0raw, src)
                           : (h == 1) ? X1[src] : X2[src];
        }
        __syncthreads();
        #pragma unroll
        for (int k = 0; k < FIN; ++k) {
            float xv = Xs[r * 9 + k];
            const float4 wa = *(const float4*)&Ws[k * HH + cg * 8];
            const float4 wb = *(const float4*)&Ws[k * HH + cg * 8 + 4];
            acc[0] += xv * wa.x; acc[1] += xv * wa.y;
            acc[2] += xv * wa.z; acc[3] += xv * wa.w;
            acc[4] += xv * wb.x; acc[5] += xv * wb.y;
            acc[6] += xv * wb.z; acc[7] += xv * wb.w;
        }
        __syncthreads();
    }
    size_t orow = (size_t)(r0 + r) * HH + cg * 8;
    float sv[8], mv[8];
    #pragma unroll
    for (int m = 0; m < 8; ++m) {
        float v = acc[m] + ldT(bias, cg * 8 + m);
        v = v > 0.f ? v : SLOPE * v;
        O[orow + m] = v;
        sv[m] = v * (1.0f / NPG);
        mv[m] = v;
    }
    pool_epilogue(g, r0 >> 8, 0, cg, r, sv, mv);
}

__global__ __launch_bounds__(256) void tagmm5_kernel(
        const void* X0raw, const float* X1, const float* X2,
        const void* W, const void* bias, float* O, float* g, const void* gamma) {
    __shared__ float Ws[FIN * HH];
    __shared__ float Xs[16 * 9];
    if (detect_bf(gamma))
        tagmm5_body<__hip_bfloat16>((const __hip_bfloat16*)X0raw, X1, X2,
                                    (const __hip_bfloat16*)W,
                                    (const __hip_bfloat16*)bias, O, g, Ws, Xs);
    else
        tagmm5_body<float>((const float*)X0raw, X1, X2, (const float*)W,
                           (const float*)bias, O, g, Ws, Xs);
}

// ---------------- tagmm128 v3 (+fused pool): thread = 4 rows x 4 cols ----------------
template <typename T>
__device__ __forceinline__ void tagmm128_body(
        const float* __restrict__ X0, const float* __restrict__ X1,
        const float* __restrict__ X2,
        const T* __restrict__ W, const T* __restrict__ bias,
        float* __restrict__ O, float* g, int gc0,
        float* Ws, float* Xs, float* psum, float* pmax) {
    int t = threadIdx.x;
    int r0 = blockIdx.x * 32;
    int cgl = t & 31;
    int rg  = t >> 5;
    float acc[4][4];
    #pragma unroll
    for (int a = 0; a < 4; ++a)
        #pragma unroll
        for (int c = 0; c < 4; ++c) acc[a][c] = 0.f;
    const float* Xh[3] = {X0, X1, X2};
    for (int h = 0; h < 3; ++h) {
        const float* X = Xh[h];
        for (int k0 = 0; k0 < HH; k0 += 64) {
            stage_chunk(Ws, W + ((size_t)h * HH + k0) * HH, 64 * HH, t);
            for (int i = t; i < 512; i += 256) {
                int row = i & 31, kq = i >> 5;
                float4 v = *(const float4*)&X[(size_t)(r0 + row) * HH + k0 + kq * 4];
                Xs[(kq * 4 + 0) * 36 + row] = v.x;
                Xs[(kq * 4 + 1) * 36 + row] = v.y;
                Xs[(kq * 4 + 2) * 36 + row] = v.z;
                Xs[(kq * 4 + 3) * 36 + row] = v.w;
            }
            __syncthreads();
            #pragma unroll 8
            for (int k = 0; k < 64; ++k) {
                const float4 xv = *(const float4*)&Xs[k * 36 + rg * 4];
                const float4 wv = *(const float4*)&Ws[k * 128 + cgl * 4];
                acc[0][0] += xv.x * wv.x; acc[0][1] += xv.x * wv.y;
                acc[0][2] += xv.x * wv.z; acc[0][3] += xv.x * wv.w;
                acc[1][0] += xv.y * wv.x; acc[1][1] += xv.y * wv.y;
                acc[1][2] += xv.y * wv.z; acc[1][3] += xv.y * wv.w;
                acc[2][0] += xv.z * wv.x; acc[2][1] += xv.z * wv.y;
                acc[2][2] += xv.z * wv.z; acc[2][3] += xv.z * wv.w;
                acc[3][0] += xv.w * wv.x; acc[3][1] += xv.w * wv.y;
                acc[3][2] += xv.w * wv.z; acc[3][3] += xv.w * wv.w;
            }
            __syncthreads();
        }
    }
    float bv[4];
    #pragma unroll
    for (int c = 0; c < 4; ++c) bv[c] = ldT(bias, cgl * 4 + c);
    float sv[4] = {0.f, 0.f, 0.f, 0.f};
    float mv[4] = {-INFINITY, -INFINITY, -INFINITY, -INFINITY};
    #pragma unroll
    for (int rr = 0; rr < 4; ++rr) {
        float4 ov;
        float* po = (float*)&ov;
        #pragma unroll
        for (int c = 0; c < 4; ++c) {
            float v = acc[rr][c] + bv[c];
            v = v > 0.f ? v : SLOPE * v;
            po[c] = v;
            sv[c] += v;
            mv[c] = fmaxf(mv[c], v);
        }
        *(float4*)&O[(size_t)(r0 + rg * 4 + rr) * HH + cgl * 4] = ov;
    }
    #pragma unroll
    for (int c = 0; c < 4; ++c) {
        sv[c] += __shfl_xor(sv[c], 32);
        mv[c] = fmaxf(mv[c], __shfl_xor(mv[c], 32));
    }
    int wave = t >> 6, lane = t & 63;
    if (lane < 32) {
        #pragma unroll
        for (int c = 0; c < 4; ++c) {
            psum[wave * 128 + cgl * 4 + c] = sv[c];
            pmax[wave * 128 + cgl * 4 + c] = mv[c];
        }
    }
    __syncthreads();
    if (t < 128) {
        float s = psum[t] + psum[128 + t] + psum[256 + t] + psum[384 + t];
        float m = fmaxf(fmaxf(pmax[t], pmax[128 + t]), fmaxf(pmax[256 + t], pmax[384 + t]));
        int b = r0 >> 8;
        atomicAdd(&g[(size_t)b * H2 + gc0 + t], s * (1.0f / NPG));
        atomicMax((unsigned*)&g[(size_t)b * H2 + gc0 + HH + t], enc_f(m));
    }
}

__global__ __launch_bounds__(256) void tagmm128_kernel(
        const float* X0, const float* X1, const float* X2,
        const void* W, const void* bias, float* O, float* g, int gc0, const void* gamma) {
    __shared__ float Ws[64 * HH];
    __shared__ float Xs[64 * 36];
    __shared__ float psum[4 * 128];
    __shared__ float pmax[4 * 128];
    if (detect_bf(gamma))
        tagmm128_body<__hip_bfloat16>(X0, X1, X2, (const __hip_bfloat16*)W,
                                      (const __hip_bfloat16*)bias, O, g, gc0,
                                      Ws, Xs, psum, pmax);
    else
        tagmm128_body<float>(X0, X1, X2, (const float*)W, (const float*)bias,
                             O, g, gc0, Ws, Xs, psum, pmax);
}

// ---------------- batchnorm: one-pass sum/sumsq, decode pool accumulators ----------------
__global__ void bn_kernel(float* __restrict__ g, const void* gamma, const void* beta) {
    int c = blockIdx.x * 128 + threadIdx.x;
    int bf = detect_bf(gamma);
    int ismax = (c & 255) >= 128;
    float s = 0.f, s2 = 0.f;
    #pragma unroll 8
    for (int b = 0; b < BB; ++b) {
        float raw = g[(size_t)b * H2 + c];
        float x = ismax ? dec_f(__float_as_uint(raw)) : raw;
        s += x; s2 += x * x;
    }
    float mu = s * (1.0f / BB);
    float var = fmaxf(s2 * (1.0f / BB) - mu * mu, 0.f);
    float rs = 1.0f / sqrtf(var + 1e-5f);
    float ga = loadin(gamma, c, bf), be = loadin(beta, c, bf);
    #pragma unroll 8
    for (int b = 0; b < BB; ++b) {
        float raw = g[(size_t)b * H2 + c];
        float x = ismax ? dec_f(__float_as_uint(raw)) : raw;
        g[(size_t)b * H2 + c] = (x - mu) * rs * ga + be;
    }
}

// ---------------- MLP layer GEMM (stride-65 scalar X reads, dbuf; measured best) --------
template <typename T>
__device__ __forceinline__ void mlp_layer_body(
        const float* __restrict__ X, const T* __restrict__ W, const T* __restrict__ bias,
        float* __restrict__ O, float* Xs0, float* Xs1, float* Ws0, float* Ws1,
        float* acc_out) {
    int t = threadIdx.x;
    int col0 = blockIdx.x * 16;
    int r = t & 63, cg = t >> 6;
    float acc[4] = {0.f, 0.f, 0.f, 0.f};
    const float4* Xg = (const float4*)X;
    float4 xr[4]; float4 wr;
    int kr = t >> 2, c4 = t & 3;
    #pragma unroll
    for (int u = 0; u < 4; ++u) {
        int i = t + u * 256;
        xr[u] = Xg[(size_t)(i >> 4) * (H2 / 4) + (i & 15)];
    }
    wr = ldT4(W + (size_t)kr * H2 + col0 + c4 * 4);
    {
        #pragma unroll
        for (int u = 0; u < 4; ++u) {
            int i = t + u * 256;
            float* d = &Xs0[(i >> 4) * 65 + (i & 15) * 4];
            d[0] = xr[u].x; d[1] = xr[u].y; d[2] = xr[u].z; d[3] = xr[u].w;
        }
        float* d = &Ws0[kr * 16 + c4 * 4];
        d[0] = wr.x; d[1] = wr.y; d[2] = wr.z; d[3] = wr.w;
    }
    __syncthreads();
    for (int s = 0; s < 12; ++s) {
        if (s + 1 < 12) {
            int k0 = (s + 1) * 64;
            #pragma unroll
            for (int u = 0; u < 4; ++u) {
                int i = t + u * 256;
                xr[u] = Xg[(size_t)(i >> 4) * (H2 / 4) + (k0 >> 2) + (i & 15)];
            }
            wr = ldT4(W + (size_t)(k0 + kr) * H2 + col0 + c4 * 4);
        }
        const float* Xc = (s & 1) ? Xs1 : Xs0;
        const float* Wc = (s & 1) ? Ws1 : Ws0;
        #pragma unroll 8
        for (int k = 0; k < 64; ++k) {
            float xv = Xc[r * 65 + k];
            const float4 wv = *(const float4*)&Wc[k * 16 + cg * 4];
            acc[0] += xv * wv.x; acc[1] += xv * wv.y;
            acc[2] += xv * wv.z; acc[3] += xv * wv.w;
        }
        if (s + 1 < 12) {
            float* Xn = (s & 1) ? Xs0 : Xs1;
            float* Wn = (s & 1) ? Ws0 : Ws1;
            #pragma unroll
            for (int u = 0; u < 4; ++u) {
                int i = t + u * 256;
                float* d = &Xn[(i >> 4) * 65 + (i & 15) * 4];
                d[0] = xr[u].x; d[1] = xr[u].y; d[2] = xr[u].z; d[3] = xr[u].w;
            }
            float* d = &Wn[kr * 16 + c4 * 4];
            d[0] = wr.x; d[1] = wr.y; d[2] = wr.z; d[3] = wr.w;
            __syncthreads();
        }
    }
    if (O) {
        size_t o = (size_t)r * H2 + col0 + cg * 4;
        #pragma unroll
        for (int m = 0; m < 4; ++m) {
            float v = acc[m] + ldT(bias, col0 + cg * 4 + m);
            O[o + m] = v > 0.f ? v : SLOPE * v;
        }
    } else {
        #pragma unroll
        for (int m = 0; m < 4; ++m) {
            float v = acc[m] + ldT(bias, col0 + cg * 4 + m);
            acc_out[m] = v > 0.f ? v : SLOPE * v;
        }
    }
}

__global__ __launch_bounds__(256) void mlp_layer_kernel(
        const float* X, const void* W, size_t woff, const void* bias, size_t boff,
        float* O, const void* gamma) {
    __shared__ float Xs0[64 * 65], Xs1[64 * 65];
    __shared__ float Ws0[64 * 16], Ws1[64 * 16];
    float dummy[4];
    if (detect_bf(gamma))
        mlp_layer_body<__hip_bfloat16>(X, (const __hip_bfloat16*)W + woff,
                                       (const __hip_bfloat16*)bias + boff, O,
                                       Xs0, Xs1, Ws0, Ws1, dummy);
    else
        mlp_layer_body<float>(X, (const float*)W + woff,
                              (const float*)bias + boff, O, Xs0, Xs1, Ws0, Ws1, dummy);
}

// ---------------- MLP last layer + fused final dot ----------------
template <typename T>
__device__ __forceinline__ void mlp_last_body(
        const float* __restrict__ X, const T* __restrict__ W, const T* __restrict__ bias,
        const T* __restrict__ ow, const T* __restrict__ ob,
        float* __restrict__ outf, unsigned* __restrict__ done, void* out, int bf,
        float* Xs0, float* Xs1, float* Ws0, float* Ws1, float* red) {
    int t = threadIdx.x;
    int col0 = blockIdx.x * 16;
    int r = t & 63, cg = t >> 6;
    float vout[4];
    mlp_layer_body<T>(X, W, bias, nullptr, Xs0, Xs1, Ws0, Ws1, vout);
    float p = 0.f;
    #pragma unroll
    for (int m = 0; m < 4; ++m)
        p += vout[m] * ldT(ow, col0 + cg * 4 + m);
    red[cg * 64 + r] = p;
    __syncthreads();
    if (t < BB) {
        float s = red[t] + red[64 + t] + red[128 + t] + red[192 + t];
        atomicAdd(&outf[t], s);
        __threadfence();
        unsigned ticket = atomicAdd(&done[t], 1u);
        if (ticket == 47u) {
            __threadfence();
            float v = outf[t] + ldT(ob, 0);
            if (bf) ((__hip_bfloat16*)out)[t] = __float2bfloat16(v);
            else    ((float*)out)[t] = v;
        }
    }
}

__global__ __launch_bounds__(256) void mlp_last_kernel(
        const float* X, const void* W, size_t woff, const void* bias, size_t boff,
        const void* ow, const void* ob, float* outf, unsigned* done, void* out,
        const void* gamma) {
    __shared__ float Xs0[64 * 65], Xs1[64 * 65];
    __shared__ float Ws0[64 * 16], Ws1[64 * 16];
    __shared__ float red[4 * 64];
    if (detect_bf(gamma))
        mlp_last_body<__hip_bfloat16>(X, (const __hip_bfloat16*)W + woff,
                                      (const __hip_bfloat16*)bias + boff,
                                      (const __hip_bfloat16*)ow, (const __hip_bfloat16*)ob,
                                      outf, done, out, 1, Xs0, Xs1, Ws0, Ws1, red);
    else
        mlp_last_body<float>(X, (const float*)W + woff, (const float*)bias + boff,
                             (const float*)ow, (const float*)ob,
                             outf, done, out, 0, Xs0, Xs1, Ws0, Ws1, red);
}

extern "C" void kernel_launch(void* const* d_in, const int* in_sizes, int n_in,
                              void* d_out, int out_size, void* d_ws, size_t ws_size,
                              hipStream_t stream) {
    const void* x_in = d_in[0];
    const void* c1w = d_in[2];  const void* c1b = d_in[3];
    const void* c2w = d_in[4];  const void* c2b = d_in[5];
    const void* c3w = d_in[6];  const void* c3b = d_in[7];
    const void* gam = d_in[8];  const void* bet = d_in[9];
    const void* lw  = d_in[10]; const void* lb  = d_in[11];
    const void* ow  = d_in[12]; const void* obb = d_in[13];

    char* w = (char*)d_ws;
    unsigned char* nbr = (unsigned char*)w;  w += (size_t)NN * KNN;
    float* t5a = (float*)w;                  w += (size_t)NN * FIN * 4;
    float* t5b = (float*)w;                  w += (size_t)NN * FIN * 4;
    float* bufA = (float*)w;                 w += (size_t)NN * HH * 4;
    float* bufB = (float*)w;                 w += (size_t)NN * HH * 4;
    float* bufC = (float*)w;                 w += (size_t)NN * HH * 4;
    float* bufD = (float*)w;                 w += (size_t)NN * HH * 4;
    float* g = (float*)w;                    w += (size_t)BB * H2 * 4;
    float* mA = (float*)w;                   w += (size_t)BB * H2 * 4;
    float* mB = (float*)w;                   w += (size_t)BB * H2 * 4;
    float* outf = (float*)w;                 w += (size_t)BB * 4;
    unsigned* done = (unsigned*)w;           w += (size_t)BB * 4;

    float dinv = 1.0f / sqrtf((float)KNN);
    float nrm = dinv * dinv;

    knn_kernel<<<NN / 4, 256, 0, stream>>>(x_in, gam, nbr, g, outf, done);

    dim3 conv_grid32(NN / 32);
    dim3 agg_grid(BB, 4, 2);

    // ---- conv1 (Cin=5) ----
    agg5x2_kernel<<<BB, 256, 0, stream>>>(x_in, gam, nbr, t5a, t5b, nrm);
    tagmm5_kernel<<<NN / 16, 256, 0, stream>>>(x_in, t5a, t5b, c1w, c1b, bufA, g, gam);

    // ---- conv2: bufA -> bufD (+pool @256) ----
    agg128_kernel<<<agg_grid, 256, 0, stream>>>(bufA, nbr, bufB, nrm);
    agg128_kernel<<<agg_grid, 256, 0, stream>>>(bufB, nbr, bufC, nrm);
    tagmm128_kernel<<<conv_grid32, 256, 0, stream>>>(bufA, bufB, bufC, c2w, c2b,
                                                     bufD, g, 256, gam);

    // ---- conv3: bufD -> bufC (+pool @512) ----
    agg128_kernel<<<agg_grid, 256, 0, stream>>>(bufD, nbr, bufA, nrm);
    agg128_kernel<<<agg_grid, 256, 0, stream>>>(bufA, nbr, bufB, nrm);
    tagmm128_kernel<<<conv_grid32, 256, 0, stream>>>(bufD, bufA, bufB, c3w, c3b,
                                                     bufC, g, 512, gam);

    // ---- batchnorm ----
    bn_kernel<<<6, 128, 0, stream>>>(g, gam, bet);

    // ---- MLP: 4 GEMM layers, then last layer + fused final dot ----
    float* src = g;
    for (int i = 0; i < 4; ++i) {
        float* dst = (i % 2 == 0) ? mA : mB;
        mlp_layer_kernel<<<H2 / 16, 256, 0, stream>>>(src, lw, (size_t)i * H2 * H2,
                                                      lb, (size_t)i * H2, dst, gam);
        src = dst;
    }
    mlp_last_kernel<<<H2 / 16, 256, 0, stream>>>(src, lw, (size_t)4 * H2 * H2,
                                                 lb, (size_t)4 * H2, ow, obb,
                                                 outf, done, d_out, gam);
}